// Round 2
// baseline (1451.063 us; speedup 1.0000x reference)
//
#include <hip/hip_runtime.h>
#include <hip/hip_bf16.h>

typedef __bf16 bf16_t;
typedef __bf16 bf16x8 __attribute__((ext_vector_type(8)));
typedef float f32x4 __attribute__((ext_vector_type(4)));

#define SEQ 2048
#define HID 2048
#define NH 16
#define DH 128
#define BATCH 2

typedef __attribute__((address_space(1))) const unsigned int g_u32;
typedef __attribute__((address_space(3))) unsigned int l_u32;
#define GLOAD_LDS16(g, l) __builtin_amdgcn_global_load_lds((g_u32*)(g), (l_u32*)(l), 16, 0, 0)

__device__ __forceinline__ unsigned short f2bf(float f) {
  return __builtin_bit_cast(unsigned short, (__bf16)f);
}

// ---------------- cast fp32 -> bf16 ----------------
__global__ void k_cast_bf16(const float4* __restrict__ in, ushort4* __restrict__ out, int n4) {
  int i = blockIdx.x * 256 + threadIdx.x;
  if (i >= n4) return;
  float4 v = in[i];
  ushort4 o;
  o.x = f2bf(v.x); o.y = f2bf(v.y); o.z = f2bf(v.z); o.w = f2bf(v.w);
  out[i] = o;
}

// ---------------- bias row means (*0.1) ----------------
__global__ void k_bmean(const float* __restrict__ bias, float* __restrict__ bm) {
  int s = blockIdx.x;
  int t = threadIdx.x;
  const float4* row = (const float4*)(bias + (size_t)s * SEQ);
  float acc = 0.f;
  for (int c = t; c < SEQ / 4; c += 256) { float4 v = row[c]; acc += (v.x + v.y) + (v.z + v.w); }
  for (int off = 1; off < 64; off <<= 1) acc += __shfl_xor(acc, off);
  __shared__ float red[4];
  if ((t & 63) == 0) red[t >> 6] = acc;
  __syncthreads();
  if (t == 0) bm[s] = (red[0] + red[1] + red[2] + red[3]) * (0.1f / SEQ);
}

// ---------------- GEMM: C[M,N] = A[M,K] @ B[N,K]^T, m97-style global_load_lds + swizzle ----------------
// EPI 0: fp32 row-major; EPI 1: bf16 row-major
template <int EPI>
__global__ __launch_bounds__(256, 2) void k_gemm_bt(const bf16_t* __restrict__ A,
                                                    const bf16_t* __restrict__ B,
                                                    void* __restrict__ C,
                                                    int M, int N, int K) {
  __shared__ ushort As[128 * 64];  // unpadded, XOR-swizzled chunks of 8 bf16
  __shared__ ushort Bs[128 * 64];
  const int tid = threadIdx.x;
  const int lane = tid & 63, wave = tid >> 6;
  const int m16 = lane & 15, quad = lane >> 4;
  const int wm = (wave >> 1) * 64, wn = (wave & 1) * 64;
  const int bm0 = blockIdx.y * 128, bn0 = blockIdx.x * 128;

  f32x4 acc[4][4];
  for (int i = 0; i < 4; ++i)
    for (int j = 0; j < 4; ++j) acc[i][j] = (f32x4){0.f, 0.f, 0.f, 0.f};

  const int NT = K / 64;
  for (int kt = 0; kt < NT; ++kt) {
    __syncthreads();
    size_t k0 = (size_t)kt * 64;
    for (int it = 0; it < 4; ++it) {
      int g = it * 256 + tid;
      int r = g >> 3;                  // 64 cols = 8 chunks/row
      int c8 = (g & 7) ^ (r & 7);      // swizzled source chunk
      int base = (it * 256 + wave * 64) * 8;  // wave-uniform LDS ushort offset
      GLOAD_LDS16(A + (size_t)(bm0 + r) * K + k0 + c8 * 8, &As[base]);
      GLOAD_LDS16(B + (size_t)(bn0 + r) * K + k0 + c8 * 8, &Bs[base]);
    }
    __syncthreads();
    for (int ks = 0; ks < 2; ++ks) {
      bf16x8 af[4], bfr[4];
      for (int i = 0; i < 4; ++i) {
        int row = wm + i * 16 + m16;
        af[i] = *(const bf16x8*)&As[row * 64 + (((ks * 4 + quad) ^ (row & 7)) * 8)];
      }
      for (int j = 0; j < 4; ++j) {
        int row = wn + j * 16 + m16;
        bfr[j] = *(const bf16x8*)&Bs[row * 64 + (((ks * 4 + quad) ^ (row & 7)) * 8)];
      }
      for (int i = 0; i < 4; ++i)
        for (int j = 0; j < 4; ++j)
          acc[i][j] = __builtin_amdgcn_mfma_f32_16x16x32_bf16(af[i], bfr[j], acc[i][j], 0, 0, 0);
    }
  }
  for (int i = 0; i < 4; ++i)
    for (int j = 0; j < 4; ++j)
      for (int r = 0; r < 4; ++r) {
        int row = bm0 + wm + i * 16 + quad * 4 + r;
        int col = bn0 + wn + j * 16 + m16;
        float v = acc[i][j][r];
        if (EPI == 0) ((float*)C)[(size_t)row * N + col] = v;
        else          ((bf16_t*)C)[(size_t)row * N + col] = (bf16_t)v;
      }
}

// ---------------- V transpose: [b,s,hid] bf16 -> [b,h,d,s] bf16 ----------------
__global__ void k_vtrans(const bf16_t* __restrict__ Vr, bf16_t* __restrict__ Vt) {
  __shared__ ushort T[64 * 72];
  const int tid = threadIdx.x;
  const int s0 = blockIdx.x * 64, c0 = blockIdx.y * 64, b = blockIdx.z;
  const int h = c0 >> 7, d0 = c0 & (DH - 1);
  int r = tid >> 2, cc = (tid & 3) * 16;
  const bf16_t* src = Vr + ((size_t)(b * SEQ + s0 + r)) * HID + c0 + cc;
  *(uint4*)&T[r * 72 + cc] = *(const uint4*)src;
  *(uint4*)&T[r * 72 + cc + 8] = *(const uint4*)(src + 8);
  __syncthreads();
  int dr = tid >> 2, sc0 = (tid & 3) * 16;
  ushort tmp[16];
  for (int e = 0; e < 16; ++e) tmp[e] = T[(sc0 + e) * 72 + dr];
  bf16_t* dst = Vt + ((size_t)(b * NH + h) * DH + d0 + dr) * SEQ + s0 + sc0;
  *(uint4*)dst = *(uint4*)&tmp[0];
  *(uint4*)(dst + 8) = *(uint4*)&tmp[8];
}

// ---------------- RoPE + bmean, fp32 -> bf16 ----------------
__global__ void k_rope(const float* __restrict__ Qf, const float* __restrict__ Kf,
                       const float* __restrict__ bm,
                       bf16_t* __restrict__ Qb, bf16_t* __restrict__ Kb) {
  int idx = blockIdx.x * 256 + threadIdx.x;
  int row = idx >> 10, p = idx & 1023;
  int h = p >> 6, i = p & 63;
  int s = row & (SEQ - 1);
  float invf = powf(10000.f, -(float)i * (1.f / 64.f));
  float ang = (float)s * invf;
  float sn, cs;
  sincosf(ang, &sn, &cs);
  float b = bm[s];
  size_t o1 = (size_t)row * HID + h * DH + i;
  size_t o2 = o1 + 64;
  float q1 = Qf[o1], q2 = Qf[o2];
  Qb[o1] = (bf16_t)(q1 * cs - q2 * sn + b);
  Qb[o2] = (bf16_t)(q2 * cs + q1 * sn + b);
  float k1 = Kf[o1], k2 = Kf[o2];
  Kb[o1] = (bf16_t)(k1 * cs - k2 * sn + b);
  Kb[o2] = (bf16_t)(k2 * cs + k1 * sn + b);
}

// ---------------- attention: barrier-free, per-wave flash ----------------
// Each wave owns 16 q-rows. Q in registers, K/V fragments loaded direct from
// global (L2-hot), bias loaded per-lane from global (L3-resident). Only LDS use
// is the wave-private P-transpose band (no cross-wave sharing -> no barriers).
// P stores are non-temporal so the 536 MB stream doesn't evict K/bias from L2/L3.
__global__ __launch_bounds__(256, 3) void k_attn(const bf16_t* __restrict__ Qb,
                                                 const bf16_t* __restrict__ Kb,
                                                 const bf16_t* __restrict__ Vt,
                                                 const float* __restrict__ bias,
                                                 float* __restrict__ P,
                                                 bf16_t* __restrict__ AO) {
  __shared__ ushort Ps[64 * 72];  // wave-private 16-row bands, stride 72

  const int tid = threadIdx.x;
  const int lane = tid & 63, wave = tid >> 6;
  const int m16 = lane & 15, quad = lane >> 4;
  const int qb = (int)gridDim.x - 1 - (int)blockIdx.x;  // big blocks first
  const int h = blockIdx.y, b = blockIdx.z;
  const int q0 = qb * 64;
  const int wq = wave * 16;
  const float scale = 0.08838834764831845f;

  // Q fragments: this lane's q-row, all 4 k-chunks (16 VGPRs)
  const bf16_t* Qg = Qb + ((size_t)(b * SEQ + q0 + wq + m16)) * HID + (size_t)h * DH;
  bf16x8 qf[4];
#pragma unroll
  for (int ks = 0; ks < 4; ++ks) qf[ks] = *(const bf16x8*)(Qg + ks * 32 + quad * 8);

  const bf16_t* Kbase = Kb + ((size_t)b * SEQ) * HID + (size_t)h * DH + quad * 8;
  // per-lane bias base: rows (q0+wq+quad*4 .. +3), col offset m16
  const float* bl = bias + (size_t)(q0 + wq + quad * 4) * SEQ + m16;

  float m_ln[4], l_ln[4];
#pragma unroll
  for (int r = 0; r < 4; ++r) { m_ln[r] = -1e30f; l_ln[r] = 0.f; }

  // ---- phase 1: exact row max / sumexp (per-lane online) ----
  for (int kt = 0; kt <= qb; ++kt) {
    const bf16_t* Kg = Kbase + (size_t)(kt * 64 + m16) * HID;
    float bv[4][4];
#pragma unroll
    for (int r = 0; r < 4; ++r)
#pragma unroll
      for (int j = 0; j < 4; ++j) bv[r][j] = bl[(size_t)r * SEQ + kt * 64 + j * 16];

    f32x4 sc[4];
#pragma unroll
    for (int j = 0; j < 4; ++j) sc[j] = (f32x4){0.f, 0.f, 0.f, 0.f};
#pragma unroll
    for (int j = 0; j < 4; ++j) {
      const bf16_t* kr = Kg + (size_t)(j * 16) * HID;
      bf16x8 k0 = *(const bf16x8*)(kr);
      bf16x8 k1 = *(const bf16x8*)(kr + 32);
      bf16x8 k2 = *(const bf16x8*)(kr + 64);
      bf16x8 k3 = *(const bf16x8*)(kr + 96);
      sc[j] = __builtin_amdgcn_mfma_f32_16x16x32_bf16(qf[0], k0, sc[j], 0, 0, 0);
      sc[j] = __builtin_amdgcn_mfma_f32_16x16x32_bf16(qf[1], k1, sc[j], 0, 0, 0);
      sc[j] = __builtin_amdgcn_mfma_f32_16x16x32_bf16(qf[2], k2, sc[j], 0, 0, 0);
      sc[j] = __builtin_amdgcn_mfma_f32_16x16x32_bf16(qf[3], k3, sc[j], 0, 0, 0);
    }
#pragma unroll
    for (int r = 0; r < 4; ++r) {
      int qi = q0 + wq + quad * 4 + r;
      float v[4], mx = m_ln[r];
#pragma unroll
      for (int j = 0; j < 4; ++j) {
        int ki = kt * 64 + j * 16 + m16;
        float xv = sc[j][r] * scale + bv[r][j];
        v[j] = (ki > qi) ? -1e30f : xv;
        mx = fmaxf(mx, v[j]);
      }
      float corr = __expf(m_ln[r] - mx);
      float s = __expf(v[0] - mx) + __expf(v[1] - mx) + __expf(v[2] - mx) + __expf(v[3] - mx);
      l_ln[r] = l_ln[r] * corr + s;
      m_ln[r] = mx;
    }
  }
  // combine across the 16 lanes sharing each row (within quad group)
  float mrow[4], linv[4];
#pragma unroll
  for (int r = 0; r < 4; ++r) {
    float m = m_ln[r], l = l_ln[r];
    for (int off = 1; off < 16; off <<= 1) {
      float mo = __shfl_xor(m, off), lo = __shfl_xor(l, off);
      float mn = fmaxf(m, mo);
      l = l * __expf(m - mn) + lo * __expf(mo - mn);
      m = mn;
    }
    mrow[r] = m; linv[r] = 1.f / l;
  }

  f32x4 oacc[8];
#pragma unroll
  for (int d = 0; d < 8; ++d) oacc[d] = (f32x4){0.f, 0.f, 0.f, 0.f};
  float* Pg = P + (((size_t)(b * NH + h)) * SEQ + q0) * SEQ;
  const bf16_t* Vbase = Vt + ((size_t)(b * NH + h)) * DH * SEQ;

  // ---- phase 2: normalized P write + PV ----
  for (int kt = 0; kt <= qb; ++kt) {
    const bf16_t* Kg = Kbase + (size_t)(kt * 64 + m16) * HID;
    float bv[4][4];
#pragma unroll
    for (int r = 0; r < 4; ++r)
#pragma unroll
      for (int j = 0; j < 4; ++j) bv[r][j] = bl[(size_t)r * SEQ + kt * 64 + j * 16];

    f32x4 sc[4];
#pragma unroll
    for (int j = 0; j < 4; ++j) sc[j] = (f32x4){0.f, 0.f, 0.f, 0.f};
#pragma unroll
    for (int j = 0; j < 4; ++j) {
      const bf16_t* kr = Kg + (size_t)(j * 16) * HID;
      bf16x8 k0 = *(const bf16x8*)(kr);
      bf16x8 k1 = *(const bf16x8*)(kr + 32);
      bf16x8 k2 = *(const bf16x8*)(kr + 64);
      bf16x8 k3 = *(const bf16x8*)(kr + 96);
      sc[j] = __builtin_amdgcn_mfma_f32_16x16x32_bf16(qf[0], k0, sc[j], 0, 0, 0);
      sc[j] = __builtin_amdgcn_mfma_f32_16x16x32_bf16(qf[1], k1, sc[j], 0, 0, 0);
      sc[j] = __builtin_amdgcn_mfma_f32_16x16x32_bf16(qf[2], k2, sc[j], 0, 0, 0);
      sc[j] = __builtin_amdgcn_mfma_f32_16x16x32_bf16(qf[3], k3, sc[j], 0, 0, 0);
    }

    // V fragments first half (issue early; latency covered by softmax below)
    bf16x8 vf0[8];
#pragma unroll
    for (int dt = 0; dt < 8; ++dt)
      vf0[dt] = *(const bf16x8*)(Vbase + (size_t)(dt * 16 + m16) * SEQ + kt * 64 + quad * 8);

#pragma unroll
    for (int r = 0; r < 4; ++r) {
      int rl = wq + quad * 4 + r, qi = q0 + rl;
#pragma unroll
      for (int j = 0; j < 4; ++j) {
        int ki = kt * 64 + j * 16 + m16;
        float xv = sc[j][r] * scale + bv[r][j];
        float p = (ki > qi) ? 0.f : __expf(xv - mrow[r]) * linv[r];
        __builtin_nontemporal_store(p, Pg + (size_t)rl * SEQ + ki);
        Ps[rl * 72 + j * 16 + m16] = f2bf(p);
      }
    }

    bf16x8 vf1[8];
#pragma unroll
    for (int dt = 0; dt < 8; ++dt)
      vf1[dt] = *(const bf16x8*)(Vbase + (size_t)(dt * 16 + m16) * SEQ + kt * 64 + 32 + quad * 8);

    {
      bf16x8 pf = *(const bf16x8*)&Ps[(wq + m16) * 72 + quad * 8];
#pragma unroll
      for (int dt = 0; dt < 8; ++dt)
        oacc[dt] = __builtin_amdgcn_mfma_f32_16x16x32_bf16(pf, vf0[dt], oacc[dt], 0, 0, 0);
      pf = *(const bf16x8*)&Ps[(wq + m16) * 72 + 32 + quad * 8];
#pragma unroll
      for (int dt = 0; dt < 8; ++dt)
        oacc[dt] = __builtin_amdgcn_mfma_f32_16x16x32_bf16(pf, vf1[dt], oacc[dt], 0, 0, 0);
    }
  }

  // attn_out (bf16, [b*S+s][h*D+d])
  bf16_t* AOg = AO + ((size_t)(b * SEQ + q0)) * HID + (size_t)h * DH;
#pragma unroll
  for (int r = 0; r < 4; ++r) {
    int rl = wq + quad * 4 + r;
#pragma unroll
    for (int dt = 0; dt < 8; ++dt)
      AOg[(size_t)rl * HID + dt * 16 + m16] = (bf16_t)oacc[dt][r];
  }

  // zero-fill masked upper-triangle columns of P (non-temporal, ext-vector type)
  int kz0 = (qb + 1) * 64;
  f32x4 z4 = (f32x4){0.f, 0.f, 0.f, 0.f};
  for (int r = 0; r < 64; ++r) {
    f32x4* dst = (f32x4*)(Pg + (size_t)r * SEQ);
    for (int c = kz0 / 4 + tid; c < SEQ / 4; c += 256)
      __builtin_nontemporal_store(z4, dst + c);
  }
}

extern "C" void kernel_launch(void* const* d_in, const int* in_sizes, int n_in,
                              void* d_out, int out_size, void* d_ws, size_t ws_size,
                              hipStream_t stream) {
  const float* x = (const float*)d_in[0];
  const float* Wq = (const float*)d_in[1];
  const float* Wk = (const float*)d_in[2];
  const float* Wv = (const float*)d_in[3];
  const float* Wo = (const float*)d_in[4];
  const float* bias = (const float*)d_in[5];

  float* out = (float*)d_out;
  float* P = out + (size_t)BATCH * SEQ * HID;  // attn_weights section (written last by k_attn)
  // park projection intermediates inside the not-yet-written P region
  float* Qf = P;
  float* Kf = P + (size_t)BATCH * SEQ * HID;
  bf16_t* Vr = (bf16_t*)(P + 2 * (size_t)BATCH * SEQ * HID);

  char* w = (char*)d_ws;
  bf16_t* xb = (bf16_t*)w;  w += (size_t)BATCH * SEQ * HID * 2;
  bf16_t* Wqb = (bf16_t*)w; w += (size_t)HID * HID * 2;
  bf16_t* Wkb = (bf16_t*)w; w += (size_t)HID * HID * 2;
  bf16_t* Wvb = (bf16_t*)w; w += (size_t)HID * HID * 2;
  bf16_t* Wob = (bf16_t*)w; w += (size_t)HID * HID * 2;
  bf16_t* Qb = (bf16_t*)w;  w += (size_t)BATCH * SEQ * HID * 2;
  bf16_t* Kb = (bf16_t*)w;  w += (size_t)BATCH * SEQ * HID * 2;
  bf16_t* Vt = (bf16_t*)w;  w += (size_t)BATCH * SEQ * HID * 2;
  bf16_t* AO = (bf16_t*)w;  w += (size_t)BATCH * SEQ * HID * 2;
  float* bm = (float*)w;    w += (size_t)SEQ * 4;

  const int n4x = BATCH * SEQ * HID / 4;
  const int n4w = HID * HID / 4;
  k_cast_bf16<<<(n4x + 255) / 256, 256, 0, stream>>>((const float4*)x, (ushort4*)xb, n4x);
  k_cast_bf16<<<(n4w + 255) / 256, 256, 0, stream>>>((const float4*)Wq, (ushort4*)Wqb, n4w);
  k_cast_bf16<<<(n4w + 255) / 256, 256, 0, stream>>>((const float4*)Wk, (ushort4*)Wkb, n4w);
  k_cast_bf16<<<(n4w + 255) / 256, 256, 0, stream>>>((const float4*)Wv, (ushort4*)Wvb, n4w);
  k_cast_bf16<<<(n4w + 255) / 256, 256, 0, stream>>>((const float4*)Wo, (ushort4*)Wob, n4w);
  k_bmean<<<SEQ, 256, 0, stream>>>(bias, bm);

  dim3 gg(HID / 128, BATCH * SEQ / 128);
  k_gemm_bt<0><<<gg, 256, 0, stream>>>(xb, Wqb, Qf, BATCH * SEQ, HID, HID);
  k_gemm_bt<0><<<gg, 256, 0, stream>>>(xb, Wkb, Kf, BATCH * SEQ, HID, HID);
  k_gemm_bt<1><<<gg, 256, 0, stream>>>(xb, Wvb, Vr, BATCH * SEQ, HID, HID);

  k_vtrans<<<dim3(SEQ / 64, HID / 64, BATCH), 256, 0, stream>>>(Vr, Vt);
  k_rope<<<(BATCH * SEQ * HID / 2) / 256, 256, 0, stream>>>(Qf, Kf, bm, Qb, Kb);

  k_attn<<<dim3(SEQ / 64, NH, BATCH), 256, 0, stream>>>(Qb, Kb, Vt, bias, P, AO);

  k_gemm_bt<0><<<gg, 256, 0, stream>>>(AO, Wob, out, BATCH * SEQ, HID, HID);
}

// Round 3
// 1028.891 us; speedup vs baseline: 1.4103x; 1.4103x over previous
//
#include <hip/hip_runtime.h>
#include <hip/hip_bf16.h>

typedef __bf16 bf16_t;
typedef __bf16 bf16x8 __attribute__((ext_vector_type(8)));
typedef float f32x4 __attribute__((ext_vector_type(4)));

#define SEQ 2048
#define HID 2048
#define NH 16
#define DH 128
#define BATCH 2

typedef __attribute__((address_space(1))) const unsigned int g_u32;
typedef __attribute__((address_space(3))) unsigned int l_u32;
#define GLOAD_LDS16(g, l) __builtin_amdgcn_global_load_lds((g_u32*)(g), (l_u32*)(l), 16, 0, 0)

__device__ __forceinline__ unsigned short f2bf(float f) {
  return __builtin_bit_cast(unsigned short, (__bf16)f);
}

// ---------------- cast fp32 -> bf16 ----------------
__global__ void k_cast_bf16(const float4* __restrict__ in, ushort4* __restrict__ out, int n4) {
  int i = blockIdx.x * 256 + threadIdx.x;
  if (i >= n4) return;
  float4 v = in[i];
  ushort4 o;
  o.x = f2bf(v.x); o.y = f2bf(v.y); o.z = f2bf(v.z); o.w = f2bf(v.w);
  out[i] = o;
}

// ---------------- bias row means (*0.1) ----------------
__global__ void k_bmean(const float* __restrict__ bias, float* __restrict__ bm) {
  int s = blockIdx.x;
  int t = threadIdx.x;
  const float4* row = (const float4*)(bias + (size_t)s * SEQ);
  float acc = 0.f;
  for (int c = t; c < SEQ / 4; c += 256) { float4 v = row[c]; acc += (v.x + v.y) + (v.z + v.w); }
  for (int off = 1; off < 64; off <<= 1) acc += __shfl_xor(acc, off);
  __shared__ float red[4];
  if ((t & 63) == 0) red[t >> 6] = acc;
  __syncthreads();
  if (t == 0) bm[s] = (red[0] + red[1] + red[2] + red[3]) * (0.1f / SEQ);
}

// ---------------- GEMM: C[M,N] = A[M,K] @ B[N,K]^T, m97-style global_load_lds + swizzle ----------------
// EPI 0: fp32 row-major; EPI 1: bf16 row-major
template <int EPI>
__global__ __launch_bounds__(256, 2) void k_gemm_bt(const bf16_t* __restrict__ A,
                                                    const bf16_t* __restrict__ B,
                                                    void* __restrict__ C,
                                                    int M, int N, int K) {
  __shared__ ushort As[128 * 64];  // unpadded, XOR-swizzled chunks of 8 bf16
  __shared__ ushort Bs[128 * 64];
  const int tid = threadIdx.x;
  const int lane = tid & 63, wave = tid >> 6;
  const int m16 = lane & 15, quad = lane >> 4;
  const int wm = (wave >> 1) * 64, wn = (wave & 1) * 64;
  const int bm0 = blockIdx.y * 128, bn0 = blockIdx.x * 128;

  f32x4 acc[4][4];
  for (int i = 0; i < 4; ++i)
    for (int j = 0; j < 4; ++j) acc[i][j] = (f32x4){0.f, 0.f, 0.f, 0.f};

  const int NT = K / 64;
  for (int kt = 0; kt < NT; ++kt) {
    __syncthreads();
    size_t k0 = (size_t)kt * 64;
    for (int it = 0; it < 4; ++it) {
      int g = it * 256 + tid;
      int r = g >> 3;                  // 64 cols = 8 chunks/row
      int c8 = (g & 7) ^ (r & 7);      // swizzled source chunk
      int base = (it * 256 + wave * 64) * 8;  // wave-uniform LDS ushort offset
      GLOAD_LDS16(A + (size_t)(bm0 + r) * K + k0 + c8 * 8, &As[base]);
      GLOAD_LDS16(B + (size_t)(bn0 + r) * K + k0 + c8 * 8, &Bs[base]);
    }
    __syncthreads();
    for (int ks = 0; ks < 2; ++ks) {
      bf16x8 af[4], bfr[4];
      for (int i = 0; i < 4; ++i) {
        int row = wm + i * 16 + m16;
        af[i] = *(const bf16x8*)&As[row * 64 + (((ks * 4 + quad) ^ (row & 7)) * 8)];
      }
      for (int j = 0; j < 4; ++j) {
        int row = wn + j * 16 + m16;
        bfr[j] = *(const bf16x8*)&Bs[row * 64 + (((ks * 4 + quad) ^ (row & 7)) * 8)];
      }
      for (int i = 0; i < 4; ++i)
        for (int j = 0; j < 4; ++j)
          acc[i][j] = __builtin_amdgcn_mfma_f32_16x16x32_bf16(af[i], bfr[j], acc[i][j], 0, 0, 0);
    }
  }
  for (int i = 0; i < 4; ++i)
    for (int j = 0; j < 4; ++j)
      for (int r = 0; r < 4; ++r) {
        int row = bm0 + wm + i * 16 + quad * 4 + r;
        int col = bn0 + wn + j * 16 + m16;
        float v = acc[i][j][r];
        if (EPI == 0) ((float*)C)[(size_t)row * N + col] = v;
        else          ((bf16_t*)C)[(size_t)row * N + col] = (bf16_t)v;
      }
}

// ---------------- V transpose: [b,s,hid] bf16 -> [b,h,d,s] bf16 ----------------
__global__ void k_vtrans(const bf16_t* __restrict__ Vr, bf16_t* __restrict__ Vt) {
  __shared__ ushort T[64 * 72];
  const int tid = threadIdx.x;
  const int s0 = blockIdx.x * 64, c0 = blockIdx.y * 64, b = blockIdx.z;
  const int h = c0 >> 7, d0 = c0 & (DH - 1);
  int r = tid >> 2, cc = (tid & 3) * 16;
  const bf16_t* src = Vr + ((size_t)(b * SEQ + s0 + r)) * HID + c0 + cc;
  *(uint4*)&T[r * 72 + cc] = *(const uint4*)src;
  *(uint4*)&T[r * 72 + cc + 8] = *(const uint4*)(src + 8);
  __syncthreads();
  int dr = tid >> 2, sc0 = (tid & 3) * 16;
  ushort tmp[16];
  for (int e = 0; e < 16; ++e) tmp[e] = T[(sc0 + e) * 72 + dr];
  bf16_t* dst = Vt + ((size_t)(b * NH + h) * DH + d0 + dr) * SEQ + s0 + sc0;
  *(uint4*)dst = *(uint4*)&tmp[0];
  *(uint4*)(dst + 8) = *(uint4*)&tmp[8];
}

// ---------------- RoPE + bmean, fp32 -> bf16 ----------------
__global__ void k_rope(const float* __restrict__ Qf, const float* __restrict__ Kf,
                       const float* __restrict__ bm,
                       bf16_t* __restrict__ Qb, bf16_t* __restrict__ Kb) {
  int idx = blockIdx.x * 256 + threadIdx.x;
  int row = idx >> 10, p = idx & 1023;
  int h = p >> 6, i = p & 63;
  int s = row & (SEQ - 1);
  float invf = powf(10000.f, -(float)i * (1.f / 64.f));
  float ang = (float)s * invf;
  float sn, cs;
  sincosf(ang, &sn, &cs);
  float b = bm[s];
  size_t o1 = (size_t)row * HID + h * DH + i;
  size_t o2 = o1 + 64;
  float q1 = Qf[o1], q2 = Qf[o2];
  Qb[o1] = (bf16_t)(q1 * cs - q2 * sn + b);
  Qb[o2] = (bf16_t)(q2 * cs + q1 * sn + b);
  float k1 = Kf[o1], k2 = Kf[o2];
  Kb[o1] = (bf16_t)(k1 * cs - k2 * sn + b);
  Kb[o2] = (bf16_t)(k2 * cs + k1 * sn + b);
}

// ---------------- attention: paired q-tiles + double-buffered LDS staging ----------------
// Each block handles q-tiles (31-bx) and (bx): uniform 33 K-tiles/phase -> no tail.
// Ks/Bs double-buffered, ONE barrier per K-tile: each tile's global_load_lds is
// issued right after a barrier and drained at the next one, a full compute phase later.
// Bias pre-cast to bf16 (Bb), staged via global_load_lds (same rounding as before).
__global__ __launch_bounds__(256, 2) void k_attn(const bf16_t* __restrict__ Qb,
                                                 const bf16_t* __restrict__ Kb,
                                                 const bf16_t* __restrict__ Vt,
                                                 const bf16_t* __restrict__ Bb,
                                                 float* __restrict__ P,
                                                 bf16_t* __restrict__ AO) {
  __shared__ ushort Qs[64 * 128];      // swizzled
  __shared__ ushort Ks[2][64 * 128];   // swizzled, double-buffered
  __shared__ ushort Bs[2][64 * 64];    // swizzled bf16 bias tile, double-buffered
  __shared__ ushort Ps[64 * 72];       // wave-private P-transpose bands

  const int tid = threadIdx.x;
  const int lane = tid & 63, wave = tid >> 6;
  const int m16 = lane & 15, quad = lane >> 4;
  const int h = blockIdx.y, b = blockIdx.z;
  const int wq = wave * 16;
  const float scale = 0.08838834764831845f;

  const bf16_t* Kbase = Kb + ((size_t)b * SEQ) * HID + (size_t)h * DH;
  const bf16_t* Vbase = Vt + ((size_t)(b * NH + h)) * DH * SEQ;

  auto stageK = [&](int kt, int buf) {
    const bf16_t* Kg = Kbase + (size_t)(kt * 64) * HID;
#pragma unroll
    for (int it = 0; it < 4; ++it) {
      int g = it * 256 + tid;
      int r = g >> 4;
      int c16 = (g & 15) ^ (r & 15);
      GLOAD_LDS16(Kg + (size_t)r * HID + c16 * 8, &Ks[buf][(it * 256 + wave * 64) * 8]);
    }
  };

  for (int half = 0; half < 2; ++half) {
    const int qt = half ? (int)blockIdx.x : 31 - (int)blockIdx.x;
    const int q0 = qt * 64;
    const bf16_t* Bgq = Bb + (size_t)q0 * SEQ;

    auto stageB = [&](int kt, int buf) {
      const bf16_t* Bg = Bgq + kt * 64;
#pragma unroll
      for (int it = 0; it < 2; ++it) {
        int g = it * 256 + tid;
        int r = g >> 3;
        int c8 = (g & 7) ^ (r & 7);
        GLOAD_LDS16(Bg + (size_t)r * SEQ + c8 * 8, &Bs[buf][(it * 256 + wave * 64) * 8]);
      }
    };

    __syncthreads();  // previous q-tile fully consumed before restaging
    const bf16_t* Qg = Qb + ((size_t)(b * SEQ + q0)) * HID + (size_t)h * DH;
#pragma unroll
    for (int it = 0; it < 4; ++it) {
      int g = it * 256 + tid;
      int r = g >> 4;
      int c16 = (g & 15) ^ (r & 15);
      GLOAD_LDS16(Qg + (size_t)r * HID + c16 * 8, &Qs[(it * 256 + wave * 64) * 8]);
    }
    stageK(0, 0);
    stageB(0, 0);

    float m_ln[4], l_ln[4];
#pragma unroll
    for (int r = 0; r < 4; ++r) { m_ln[r] = -1e30f; l_ln[r] = 0.f; }

    // ---- phase 1: exact row max / sumexp ----
    for (int kt = 0; kt <= qt; ++kt) {
      const int cur = kt & 1;
      __syncthreads();  // drains tile-kt staging (issued one full tile ago)
      if (kt < qt) { stageK(kt + 1, cur ^ 1); stageB(kt + 1, cur ^ 1); }

      f32x4 sc[4];
#pragma unroll
      for (int j = 0; j < 4; ++j) sc[j] = (f32x4){0.f, 0.f, 0.f, 0.f};
#pragma unroll
      for (int ks = 0; ks < 4; ++ks) {
        int qrow = wq + m16;
        bf16x8 af = *(const bf16x8*)&Qs[qrow * 128 + (((ks * 4 + quad) ^ (qrow & 15)) * 8)];
#pragma unroll
        for (int j = 0; j < 4; ++j) {
          int krow = j * 16 + m16;
          bf16x8 bfr = *(const bf16x8*)&Ks[cur][krow * 128 + (((ks * 4 + quad) ^ (krow & 15)) * 8)];
          sc[j] = __builtin_amdgcn_mfma_f32_16x16x32_bf16(af, bfr, sc[j], 0, 0, 0);
        }
      }
#pragma unroll
      for (int r = 0; r < 4; ++r) {
        int rl = wq + quad * 4 + r, qi = q0 + rl;
        float v[4], mx = m_ln[r];
#pragma unroll
        for (int j = 0; j < 4; ++j) {
          int c = j * 16 + m16;
          int ki = kt * 64 + c;
          float bv = (float)(*(const bf16_t*)&Bs[cur][rl * 64 + (((c >> 3) ^ (rl & 7)) << 3) + (c & 7)]);
          float xv = sc[j][r] * scale + bv;
          v[j] = (ki > qi) ? -1e30f : xv;
          mx = fmaxf(mx, v[j]);
        }
        float corr = __expf(m_ln[r] - mx);
        float s = __expf(v[0] - mx) + __expf(v[1] - mx) + __expf(v[2] - mx) + __expf(v[3] - mx);
        l_ln[r] = l_ln[r] * corr + s;
        m_ln[r] = mx;
      }
    }
    // combine across the 16 lanes sharing each row
    float mrow[4], linv[4];
#pragma unroll
    for (int r = 0; r < 4; ++r) {
      float m = m_ln[r], l = l_ln[r];
      for (int off = 1; off < 16; off <<= 1) {
        float mo = __shfl_xor(m, off), lo = __shfl_xor(l, off);
        float mn = fmaxf(m, mo);
        l = l * __expf(m - mn) + lo * __expf(mo - mn);
        m = mn;
      }
      mrow[r] = m; linv[r] = 1.f / l;
    }

    // ---- phase 2: normalized P write + PV ----
    __syncthreads();  // all waves done reading phase-1 buffers
    stageK(0, 0);
    stageB(0, 0);

    f32x4 oacc[8];
#pragma unroll
    for (int d = 0; d < 8; ++d) oacc[d] = (f32x4){0.f, 0.f, 0.f, 0.f};
    float* Pg = P + (((size_t)(b * NH + h)) * SEQ + q0) * SEQ;

    for (int kt = 0; kt <= qt; ++kt) {
      const int cur = kt & 1;
      __syncthreads();
      if (kt < qt) { stageK(kt + 1, cur ^ 1); stageB(kt + 1, cur ^ 1); }

      f32x4 sc[4];
#pragma unroll
      for (int j = 0; j < 4; ++j) sc[j] = (f32x4){0.f, 0.f, 0.f, 0.f};
#pragma unroll
      for (int ks = 0; ks < 4; ++ks) {
        int qrow = wq + m16;
        bf16x8 af = *(const bf16x8*)&Qs[qrow * 128 + (((ks * 4 + quad) ^ (qrow & 15)) * 8)];
#pragma unroll
        for (int j = 0; j < 4; ++j) {
          int krow = j * 16 + m16;
          bf16x8 bfr = *(const bf16x8*)&Ks[cur][krow * 128 + (((ks * 4 + quad) ^ (krow & 15)) * 8)];
          sc[j] = __builtin_amdgcn_mfma_f32_16x16x32_bf16(af, bfr, sc[j], 0, 0, 0);
        }
      }

      // V fragments first half (issue early; latency covered by softmax below)
      bf16x8 vf0[8];
#pragma unroll
      for (int dt = 0; dt < 8; ++dt)
        vf0[dt] = *(const bf16x8*)(Vbase + (size_t)(dt * 16 + m16) * SEQ + kt * 64 + quad * 8);

#pragma unroll
      for (int r = 0; r < 4; ++r) {
        int rl = wq + quad * 4 + r, qi = q0 + rl;
#pragma unroll
        for (int j = 0; j < 4; ++j) {
          int c = j * 16 + m16;
          int ki = kt * 64 + c;
          float bv = (float)(*(const bf16_t*)&Bs[cur][rl * 64 + (((c >> 3) ^ (rl & 7)) << 3) + (c & 7)]);
          float xv = sc[j][r] * scale + bv;
          float p = (ki > qi) ? 0.f : __expf(xv - mrow[r]) * linv[r];
          Pg[(size_t)rl * SEQ + ki] = p;
          Ps[rl * 72 + j * 16 + m16] = f2bf(p);
        }
      }

      bf16x8 vf1[8];
#pragma unroll
      for (int dt = 0; dt < 8; ++dt)
        vf1[dt] = *(const bf16x8*)(Vbase + (size_t)(dt * 16 + m16) * SEQ + kt * 64 + 32 + quad * 8);

      {
        bf16x8 pf = *(const bf16x8*)&Ps[(wq + m16) * 72 + quad * 8];
#pragma unroll
        for (int dt = 0; dt < 8; ++dt)
          oacc[dt] = __builtin_amdgcn_mfma_f32_16x16x32_bf16(pf, vf0[dt], oacc[dt], 0, 0, 0);
        pf = *(const bf16x8*)&Ps[(wq + m16) * 72 + 32 + quad * 8];
#pragma unroll
        for (int dt = 0; dt < 8; ++dt)
          oacc[dt] = __builtin_amdgcn_mfma_f32_16x16x32_bf16(pf, vf1[dt], oacc[dt], 0, 0, 0);
      }
    }

    // attn_out (bf16, [b*S+s][h*D+d])
    bf16_t* AOg = AO + ((size_t)(b * SEQ + q0)) * HID + (size_t)h * DH;
#pragma unroll
    for (int r = 0; r < 4; ++r) {
      int rl = wq + quad * 4 + r;
#pragma unroll
      for (int dt = 0; dt < 8; ++dt)
        AOg[(size_t)rl * HID + dt * 16 + m16] = (bf16_t)oacc[dt][r];
    }

    // zero-fill masked upper-triangle columns of P
    int kz0 = (qt + 1) * 64;
    for (int r = 0; r < 64; ++r) {
      float4* dst = (float4*)(Pg + (size_t)r * SEQ);
      for (int c = kz0 / 4 + tid; c < SEQ / 4; c += 256) dst[c] = make_float4(0.f, 0.f, 0.f, 0.f);
    }
  }
}

extern "C" void kernel_launch(void* const* d_in, const int* in_sizes, int n_in,
                              void* d_out, int out_size, void* d_ws, size_t ws_size,
                              hipStream_t stream) {
  const float* x = (const float*)d_in[0];
  const float* Wq = (const float*)d_in[1];
  const float* Wk = (const float*)d_in[2];
  const float* Wv = (const float*)d_in[3];
  const float* Wo = (const float*)d_in[4];
  const float* bias = (const float*)d_in[5];

  float* out = (float*)d_out;
  float* P = out + (size_t)BATCH * SEQ * HID;  // attn_weights section (written last by k_attn)
  // park projection intermediates inside the not-yet-written P region
  float* Qf = P;
  float* Kf = P + (size_t)BATCH * SEQ * HID;
  bf16_t* Vr = (bf16_t*)(P + 2 * (size_t)BATCH * SEQ * HID);

  char* w = (char*)d_ws;
  bf16_t* xb = (bf16_t*)w;  w += (size_t)BATCH * SEQ * HID * 2;
  bf16_t* Wqb = (bf16_t*)w; w += (size_t)HID * HID * 2;
  bf16_t* Wkb = (bf16_t*)w; w += (size_t)HID * HID * 2;
  bf16_t* Wvb = (bf16_t*)w; w += (size_t)HID * HID * 2;
  bf16_t* Wob = (bf16_t*)w; w += (size_t)HID * HID * 2;
  bf16_t* Qb = (bf16_t*)w;  w += (size_t)BATCH * SEQ * HID * 2;
  bf16_t* Kb = (bf16_t*)w;  w += (size_t)BATCH * SEQ * HID * 2;
  bf16_t* Vt = (bf16_t*)w;  w += (size_t)BATCH * SEQ * HID * 2;
  bf16_t* AO = (bf16_t*)w;  w += (size_t)BATCH * SEQ * HID * 2;
  float* bm = (float*)w;    w += (size_t)SEQ * 4;
  // bf16 bias reuses the xb slot (xb dead after the projection GEMMs; 8 MB <= 16 MB)
  bf16_t* Bb = xb;

  const int n4x = BATCH * SEQ * HID / 4;
  const int n4w = HID * HID / 4;
  const int n4b = SEQ * SEQ / 4;
  k_cast_bf16<<<(n4x + 255) / 256, 256, 0, stream>>>((const float4*)x, (ushort4*)xb, n4x);
  k_cast_bf16<<<(n4w + 255) / 256, 256, 0, stream>>>((const float4*)Wq, (ushort4*)Wqb, n4w);
  k_cast_bf16<<<(n4w + 255) / 256, 256, 0, stream>>>((const float4*)Wk, (ushort4*)Wkb, n4w);
  k_cast_bf16<<<(n4w + 255) / 256, 256, 0, stream>>>((const float4*)Wv, (ushort4*)Wvb, n4w);
  k_cast_bf16<<<(n4w + 255) / 256, 256, 0, stream>>>((const float4*)Wo, (ushort4*)Wob, n4w);
  k_bmean<<<SEQ, 256, 0, stream>>>(bias, bm);

  dim3 gg(HID / 128, BATCH * SEQ / 128);
  k_gemm_bt<0><<<gg, 256, 0, stream>>>(xb, Wqb, Qf, BATCH * SEQ, HID, HID);
  k_gemm_bt<0><<<gg, 256, 0, stream>>>(xb, Wkb, Kf, BATCH * SEQ, HID, HID);
  k_gemm_bt<1><<<gg, 256, 0, stream>>>(xb, Wvb, Vr, BATCH * SEQ, HID, HID);

  // xb is dead now; cast bias (fp32) -> bf16 into its slot
  k_cast_bf16<<<(n4b + 255) / 256, 256, 0, stream>>>((const float4*)bias, (ushort4*)Bb, n4b);

  k_vtrans<<<dim3(SEQ / 64, HID / 64, BATCH), 256, 0, stream>>>(Vr, Vt);
  k_rope<<<(BATCH * SEQ * HID / 2) / 256, 256, 0, stream>>>(Qf, Kf, bm, Qb, Kb);

  k_attn<<<dim3(16, NH, BATCH), 256, 0, stream>>>(Qb, Kb, Vt, Bb, P, AO);

  k_gemm_bt<0><<<gg, 256, 0, stream>>>(AO, Wob, out, BATCH * SEQ, HID, HID);
}

// Round 4
// 991.335 us; speedup vs baseline: 1.4637x; 1.0379x over previous
//
#include <hip/hip_runtime.h>
#include <hip/hip_bf16.h>

typedef __bf16 bf16_t;
typedef __bf16 bf16x8 __attribute__((ext_vector_type(8)));
typedef float f32x4 __attribute__((ext_vector_type(4)));

#define SEQ 2048
#define HID 2048
#define NH 16
#define DH 128
#define BATCH 2

typedef __attribute__((address_space(1))) const unsigned int g_u32;
typedef __attribute__((address_space(3))) unsigned int l_u32;
#define GLOAD_LDS16(g, l) __builtin_amdgcn_global_load_lds((g_u32*)(g), (l_u32*)(l), 16, 0, 0)

__device__ __forceinline__ unsigned short f2bf(float f) {
  return __builtin_bit_cast(unsigned short, (__bf16)f);
}

// ---------------- cast fp32 -> bf16 ----------------
__global__ void k_cast_bf16(const float4* __restrict__ in, ushort4* __restrict__ out, int n4) {
  int i = blockIdx.x * 256 + threadIdx.x;
  if (i >= n4) return;
  float4 v = in[i];
  ushort4 o;
  o.x = f2bf(v.x); o.y = f2bf(v.y); o.z = f2bf(v.z); o.w = f2bf(v.w);
  out[i] = o;
}

// ---------------- bias row means (*0.1) ----------------
__global__ void k_bmean(const float* __restrict__ bias, float* __restrict__ bm) {
  int s = blockIdx.x;
  int t = threadIdx.x;
  const float4* row = (const float4*)(bias + (size_t)s * SEQ);
  float acc = 0.f;
  for (int c = t; c < SEQ / 4; c += 256) { float4 v = row[c]; acc += (v.x + v.y) + (v.z + v.w); }
  for (int off = 1; off < 64; off <<= 1) acc += __shfl_xor(acc, off);
  __shared__ float red[4];
  if ((t & 63) == 0) red[t >> 6] = acc;
  __syncthreads();
  if (t == 0) bm[s] = (red[0] + red[1] + red[2] + red[3]) * (0.1f / SEQ);
}

// ---------------- GEMM: C[M,N] = A[M,K] @ B[N,K]^T, m97-style global_load_lds + swizzle ----------------
// EPI 0: fp32 row-major; EPI 1: bf16 row-major
template <int EPI>
__global__ __launch_bounds__(256, 2) void k_gemm_bt(const bf16_t* __restrict__ A,
                                                    const bf16_t* __restrict__ B,
                                                    void* __restrict__ C,
                                                    int M, int N, int K) {
  __shared__ ushort As[128 * 64];  // unpadded, XOR-swizzled chunks of 8 bf16
  __shared__ ushort Bs[128 * 64];
  const int tid = threadIdx.x;
  const int lane = tid & 63, wave = tid >> 6;
  const int m16 = lane & 15, quad = lane >> 4;
  const int wm = (wave >> 1) * 64, wn = (wave & 1) * 64;
  const int bm0 = blockIdx.y * 128, bn0 = blockIdx.x * 128;

  f32x4 acc[4][4];
  for (int i = 0; i < 4; ++i)
    for (int j = 0; j < 4; ++j) acc[i][j] = (f32x4){0.f, 0.f, 0.f, 0.f};

  const int NT = K / 64;
  for (int kt = 0; kt < NT; ++kt) {
    __syncthreads();
    size_t k0 = (size_t)kt * 64;
    for (int it = 0; it < 4; ++it) {
      int g = it * 256 + tid;
      int r = g >> 3;                  // 64 cols = 8 chunks/row
      int c8 = (g & 7) ^ (r & 7);      // swizzled source chunk
      int base = (it * 256 + wave * 64) * 8;  // wave-uniform LDS ushort offset
      GLOAD_LDS16(A + (size_t)(bm0 + r) * K + k0 + c8 * 8, &As[base]);
      GLOAD_LDS16(B + (size_t)(bn0 + r) * K + k0 + c8 * 8, &Bs[base]);
    }
    __syncthreads();
    for (int ks = 0; ks < 2; ++ks) {
      bf16x8 af[4], bfr[4];
      for (int i = 0; i < 4; ++i) {
        int row = wm + i * 16 + m16;
        af[i] = *(const bf16x8*)&As[row * 64 + (((ks * 4 + quad) ^ (row & 7)) * 8)];
      }
      for (int j = 0; j < 4; ++j) {
        int row = wn + j * 16 + m16;
        bfr[j] = *(const bf16x8*)&Bs[row * 64 + (((ks * 4 + quad) ^ (row & 7)) * 8)];
      }
      for (int i = 0; i < 4; ++i)
        for (int j = 0; j < 4; ++j)
          acc[i][j] = __builtin_amdgcn_mfma_f32_16x16x32_bf16(af[i], bfr[j], acc[i][j], 0, 0, 0);
    }
  }
  for (int i = 0; i < 4; ++i)
    for (int j = 0; j < 4; ++j)
      for (int r = 0; r < 4; ++r) {
        int row = bm0 + wm + i * 16 + quad * 4 + r;
        int col = bn0 + wn + j * 16 + m16;
        float v = acc[i][j][r];
        if (EPI == 0) ((float*)C)[(size_t)row * N + col] = v;
        else          ((bf16_t*)C)[(size_t)row * N + col] = (bf16_t)v;
      }
}

// ---------------- fused QKV GEMM: A[4096,2048] @ Wqkv[6144,2048]^T ----------------
// Wq/Wk/Wv bf16 copies are contiguous in workspace -> one [6144,2048] B matrix.
// Epilogue region per 2048-col band: Q -> fp32, K -> fp32, V -> bf16.
__global__ __launch_bounds__(256, 2) void k_gemm_qkv(const bf16_t* __restrict__ A,
                                                     const bf16_t* __restrict__ B,
                                                     float* __restrict__ Qf,
                                                     float* __restrict__ Kf,
                                                     bf16_t* __restrict__ Vr) {
  __shared__ ushort As[128 * 64];
  __shared__ ushort Bs[128 * 64];
  const int tid = threadIdx.x;
  const int lane = tid & 63, wave = tid >> 6;
  const int m16 = lane & 15, quad = lane >> 4;
  const int wm = (wave >> 1) * 64, wn = (wave & 1) * 64;
  const int bm0 = blockIdx.y * 128, bn0 = blockIdx.x * 128;
  const int K = HID;

  f32x4 acc[4][4];
  for (int i = 0; i < 4; ++i)
    for (int j = 0; j < 4; ++j) acc[i][j] = (f32x4){0.f, 0.f, 0.f, 0.f};

  const int NT = K / 64;
  for (int kt = 0; kt < NT; ++kt) {
    __syncthreads();
    size_t k0 = (size_t)kt * 64;
    for (int it = 0; it < 4; ++it) {
      int g = it * 256 + tid;
      int r = g >> 3;
      int c8 = (g & 7) ^ (r & 7);
      int base = (it * 256 + wave * 64) * 8;
      GLOAD_LDS16(A + (size_t)(bm0 + r) * K + k0 + c8 * 8, &As[base]);
      GLOAD_LDS16(B + (size_t)(bn0 + r) * K + k0 + c8 * 8, &Bs[base]);
    }
    __syncthreads();
    for (int ks = 0; ks < 2; ++ks) {
      bf16x8 af[4], bfr[4];
      for (int i = 0; i < 4; ++i) {
        int row = wm + i * 16 + m16;
        af[i] = *(const bf16x8*)&As[row * 64 + (((ks * 4 + quad) ^ (row & 7)) * 8)];
      }
      for (int j = 0; j < 4; ++j) {
        int row = wn + j * 16 + m16;
        bfr[j] = *(const bf16x8*)&Bs[row * 64 + (((ks * 4 + quad) ^ (row & 7)) * 8)];
      }
      for (int i = 0; i < 4; ++i)
        for (int j = 0; j < 4; ++j)
          acc[i][j] = __builtin_amdgcn_mfma_f32_16x16x32_bf16(af[i], bfr[j], acc[i][j], 0, 0, 0);
    }
  }
  const int region = bn0 >> 11;  // 0:Q 1:K 2:V (uniform per block)
  for (int i = 0; i < 4; ++i)
    for (int j = 0; j < 4; ++j)
      for (int r = 0; r < 4; ++r) {
        int row = bm0 + wm + i * 16 + quad * 4 + r;
        int cl = (bn0 + wn + j * 16 + m16) & (HID - 1);
        float v = acc[i][j][r];
        if (region == 0)      Qf[(size_t)row * HID + cl] = v;
        else if (region == 1) Kf[(size_t)row * HID + cl] = v;
        else                  Vr[(size_t)row * HID + cl] = (bf16_t)v;
      }
}

// ---------------- V transpose: [b,s,hid] bf16 -> [b,h,d,s] bf16 ----------------
__global__ void k_vtrans(const bf16_t* __restrict__ Vr, bf16_t* __restrict__ Vt) {
  __shared__ ushort T[64 * 72];
  const int tid = threadIdx.x;
  const int s0 = blockIdx.x * 64, c0 = blockIdx.y * 64, b = blockIdx.z;
  const int h = c0 >> 7, d0 = c0 & (DH - 1);
  int r = tid >> 2, cc = (tid & 3) * 16;
  const bf16_t* src = Vr + ((size_t)(b * SEQ + s0 + r)) * HID + c0 + cc;
  *(uint4*)&T[r * 72 + cc] = *(const uint4*)src;
  *(uint4*)&T[r * 72 + cc + 8] = *(const uint4*)(src + 8);
  __syncthreads();
  int dr = tid >> 2, sc0 = (tid & 3) * 16;
  ushort tmp[16];
  for (int e = 0; e < 16; ++e) tmp[e] = T[(sc0 + e) * 72 + dr];
  bf16_t* dst = Vt + ((size_t)(b * NH + h) * DH + d0 + dr) * SEQ + s0 + sc0;
  *(uint4*)dst = *(uint4*)&tmp[0];
  *(uint4*)(dst + 8) = *(uint4*)&tmp[8];
}

// ---------------- RoPE + bmean, fp32 -> bf16 (vectorized: 4 pairs/thread) ----------------
__global__ void k_rope(const float* __restrict__ Qf, const float* __restrict__ Kf,
                       const float* __restrict__ bm,
                       bf16_t* __restrict__ Qb, bf16_t* __restrict__ Kb) {
  int idx = blockIdx.x * 256 + threadIdx.x;   // B*S*HID/8 threads
  int row = idx >> 8;                         // 256 4-pair groups per row
  int p = idx & 255;
  int h = p >> 4, i0 = (p & 15) * 4;
  int s = row & (SEQ - 1);
  float b = bm[s];
  size_t o1 = (size_t)row * HID + h * DH + i0;
  size_t o2 = o1 + 64;
  float4 q1 = *(const float4*)(Qf + o1);
  float4 q2 = *(const float4*)(Qf + o2);
  float4 k1 = *(const float4*)(Kf + o1);
  float4 k2 = *(const float4*)(Kf + o2);
  ushort4 q1o, q2o, k1o, k2o;
#pragma unroll
  for (int e = 0; e < 4; ++e) {
    // 10000^(-i/64) = 2^(-i * log2(10000)/64)
    float invf = exp2f((float)(i0 + e) * -0.2076205059304601f);
    float ang = (float)s * invf;
    float sn, cs;
    sincosf(ang, &sn, &cs);
    float q1e = (&q1.x)[e], q2e = (&q2.x)[e];
    float k1e = (&k1.x)[e], k2e = (&k2.x)[e];
    (&q1o.x)[e] = f2bf(q1e * cs - q2e * sn + b);
    (&q2o.x)[e] = f2bf(q2e * cs + q1e * sn + b);
    (&k1o.x)[e] = f2bf(k1e * cs - k2e * sn + b);
    (&k2o.x)[e] = f2bf(k2e * cs + k1e * sn + b);
  }
  *(ushort4*)(Qb + o1) = q1o;
  *(ushort4*)(Qb + o2) = q2o;
  *(ushort4*)(Kb + o1) = k1o;
  *(ushort4*)(Kb + o2) = k2o;
}

// ---------------- attention: paired q-tiles + double-buffered LDS staging ----------------
__global__ __launch_bounds__(256, 2) void k_attn(const bf16_t* __restrict__ Qb,
                                                 const bf16_t* __restrict__ Kb,
                                                 const bf16_t* __restrict__ Vt,
                                                 const bf16_t* __restrict__ Bb,
                                                 float* __restrict__ P,
                                                 bf16_t* __restrict__ AO) {
  __shared__ ushort Qs[64 * 128];      // swizzled
  __shared__ ushort Ks[2][64 * 128];   // swizzled, double-buffered
  __shared__ ushort Bs[2][64 * 64];    // swizzled bf16 bias tile, double-buffered
  __shared__ ushort Ps[64 * 72];       // wave-private P-transpose bands

  const int tid = threadIdx.x;
  const int lane = tid & 63, wave = tid >> 6;
  const int m16 = lane & 15, quad = lane >> 4;
  const int h = blockIdx.y, b = blockIdx.z;
  const int wq = wave * 16;
  const float scale = 0.08838834764831845f;

  const bf16_t* Kbase = Kb + ((size_t)b * SEQ) * HID + (size_t)h * DH;
  const bf16_t* Vbase = Vt + ((size_t)(b * NH + h)) * DH * SEQ;

  auto stageK = [&](int kt, int buf) {
    const bf16_t* Kg = Kbase + (size_t)(kt * 64) * HID;
#pragma unroll
    for (int it = 0; it < 4; ++it) {
      int g = it * 256 + tid;
      int r = g >> 4;
      int c16 = (g & 15) ^ (r & 15);
      GLOAD_LDS16(Kg + (size_t)r * HID + c16 * 8, &Ks[buf][(it * 256 + wave * 64) * 8]);
    }
  };

  for (int half = 0; half < 2; ++half) {
    const int qt = half ? (int)blockIdx.x : 31 - (int)blockIdx.x;
    const int q0 = qt * 64;
    const bf16_t* Bgq = Bb + (size_t)q0 * SEQ;

    auto stageB = [&](int kt, int buf) {
      const bf16_t* Bg = Bgq + kt * 64;
#pragma unroll
      for (int it = 0; it < 2; ++it) {
        int g = it * 256 + tid;
        int r = g >> 3;
        int c8 = (g & 7) ^ (r & 7);
        GLOAD_LDS16(Bg + (size_t)r * SEQ + c8 * 8, &Bs[buf][(it * 256 + wave * 64) * 8]);
      }
    };

    __syncthreads();  // previous q-tile fully consumed before restaging
    const bf16_t* Qg = Qb + ((size_t)(b * SEQ + q0)) * HID + (size_t)h * DH;
#pragma unroll
    for (int it = 0; it < 4; ++it) {
      int g = it * 256 + tid;
      int r = g >> 4;
      int c16 = (g & 15) ^ (r & 15);
      GLOAD_LDS16(Qg + (size_t)r * HID + c16 * 8, &Qs[(it * 256 + wave * 64) * 8]);
    }
    stageK(0, 0);
    stageB(0, 0);

    float m_ln[4], l_ln[4];
#pragma unroll
    for (int r = 0; r < 4; ++r) { m_ln[r] = -1e30f; l_ln[r] = 0.f; }

    // ---- phase 1: exact row max / sumexp ----
    for (int kt = 0; kt <= qt; ++kt) {
      const int cur = kt & 1;
      __syncthreads();  // drains tile-kt staging (issued one full tile ago)
      if (kt < qt) { stageK(kt + 1, cur ^ 1); stageB(kt + 1, cur ^ 1); }

      f32x4 sc[4];
#pragma unroll
      for (int j = 0; j < 4; ++j) sc[j] = (f32x4){0.f, 0.f, 0.f, 0.f};
#pragma unroll
      for (int ks = 0; ks < 4; ++ks) {
        int qrow = wq + m16;
        bf16x8 af = *(const bf16x8*)&Qs[qrow * 128 + (((ks * 4 + quad) ^ (qrow & 15)) * 8)];
#pragma unroll
        for (int j = 0; j < 4; ++j) {
          int krow = j * 16 + m16;
          bf16x8 bfr = *(const bf16x8*)&Ks[cur][krow * 128 + (((ks * 4 + quad) ^ (krow & 15)) * 8)];
          sc[j] = __builtin_amdgcn_mfma_f32_16x16x32_bf16(af, bfr, sc[j], 0, 0, 0);
        }
      }
#pragma unroll
      for (int r = 0; r < 4; ++r) {
        int rl = wq + quad * 4 + r, qi = q0 + rl;
        float v[4], mx = m_ln[r];
#pragma unroll
        for (int j = 0; j < 4; ++j) {
          int c = j * 16 + m16;
          int ki = kt * 64 + c;
          float bv = (float)(*(const bf16_t*)&Bs[cur][rl * 64 + (((c >> 3) ^ (rl & 7)) << 3) + (c & 7)]);
          float xv = sc[j][r] * scale + bv;
          v[j] = (ki > qi) ? -1e30f : xv;
          mx = fmaxf(mx, v[j]);
        }
        float corr = __expf(m_ln[r] - mx);
        float s = __expf(v[0] - mx) + __expf(v[1] - mx) + __expf(v[2] - mx) + __expf(v[3] - mx);
        l_ln[r] = l_ln[r] * corr + s;
        m_ln[r] = mx;
      }
    }
    // combine across the 16 lanes sharing each row
    float mrow[4], linv[4];
#pragma unroll
    for (int r = 0; r < 4; ++r) {
      float m = m_ln[r], l = l_ln[r];
      for (int off = 1; off < 16; off <<= 1) {
        float mo = __shfl_xor(m, off), lo = __shfl_xor(l, off);
        float mn = fmaxf(m, mo);
        l = l * __expf(m - mn) + lo * __expf(mo - mn);
        m = mn;
      }
      mrow[r] = m; linv[r] = 1.f / l;
    }

    // ---- phase 2: normalized P write + PV ----
    __syncthreads();  // all waves done reading phase-1 buffers
    stageK(0, 0);
    stageB(0, 0);

    f32x4 oacc[8];
#pragma unroll
    for (int d = 0; d < 8; ++d) oacc[d] = (f32x4){0.f, 0.f, 0.f, 0.f};
    float* Pg = P + (((size_t)(b * NH + h)) * SEQ + q0) * SEQ;

    for (int kt = 0; kt <= qt; ++kt) {
      const int cur = kt & 1;
      __syncthreads();
      if (kt < qt) { stageK(kt + 1, cur ^ 1); stageB(kt + 1, cur ^ 1); }

      f32x4 sc[4];
#pragma unroll
      for (int j = 0; j < 4; ++j) sc[j] = (f32x4){0.f, 0.f, 0.f, 0.f};
#pragma unroll
      for (int ks = 0; ks < 4; ++ks) {
        int qrow = wq + m16;
        bf16x8 af = *(const bf16x8*)&Qs[qrow * 128 + (((ks * 4 + quad) ^ (qrow & 15)) * 8)];
#pragma unroll
        for (int j = 0; j < 4; ++j) {
          int krow = j * 16 + m16;
          bf16x8 bfr = *(const bf16x8*)&Ks[cur][krow * 128 + (((ks * 4 + quad) ^ (krow & 15)) * 8)];
          sc[j] = __builtin_amdgcn_mfma_f32_16x16x32_bf16(af, bfr, sc[j], 0, 0, 0);
        }
      }

      // V fragments first half (issue early; latency covered by softmax below)
      bf16x8 vf0[8];
#pragma unroll
      for (int dt = 0; dt < 8; ++dt)
        vf0[dt] = *(const bf16x8*)(Vbase + (size_t)(dt * 16 + m16) * SEQ + kt * 64 + quad * 8);

#pragma unroll
      for (int r = 0; r < 4; ++r) {
        int rl = wq + quad * 4 + r, qi = q0 + rl;
#pragma unroll
        for (int j = 0; j < 4; ++j) {
          int c = j * 16 + m16;
          int ki = kt * 64 + c;
          float bv = (float)(*(const bf16_t*)&Bs[cur][rl * 64 + (((c >> 3) ^ (rl & 7)) << 3) + (c & 7)]);
          float xv = sc[j][r] * scale + bv;
          float p = (ki > qi) ? 0.f : __expf(xv - mrow[r]) * linv[r];
          Pg[(size_t)rl * SEQ + ki] = p;
          Ps[rl * 72 + j * 16 + m16] = f2bf(p);
        }
      }

      bf16x8 vf1[8];
#pragma unroll
      for (int dt = 0; dt < 8; ++dt)
        vf1[dt] = *(const bf16x8*)(Vbase + (size_t)(dt * 16 + m16) * SEQ + kt * 64 + 32 + quad * 8);

      {
        bf16x8 pf = *(const bf16x8*)&Ps[(wq + m16) * 72 + quad * 8];
#pragma unroll
        for (int dt = 0; dt < 8; ++dt)
          oacc[dt] = __builtin_amdgcn_mfma_f32_16x16x32_bf16(pf, vf0[dt], oacc[dt], 0, 0, 0);
        pf = *(const bf16x8*)&Ps[(wq + m16) * 72 + 32 + quad * 8];
#pragma unroll
        for (int dt = 0; dt < 8; ++dt)
          oacc[dt] = __builtin_amdgcn_mfma_f32_16x16x32_bf16(pf, vf1[dt], oacc[dt], 0, 0, 0);
      }
    }

    // attn_out (bf16, [b*S+s][h*D+d])
    bf16_t* AOg = AO + ((size_t)(b * SEQ + q0)) * HID + (size_t)h * DH;
#pragma unroll
    for (int r = 0; r < 4; ++r) {
      int rl = wq + quad * 4 + r;
#pragma unroll
      for (int dt = 0; dt < 8; ++dt)
        AOg[(size_t)rl * HID + dt * 16 + m16] = (bf16_t)oacc[dt][r];
    }

    // zero-fill masked upper-triangle columns of P
    int kz0 = (qt + 1) * 64;
    for (int r = 0; r < 64; ++r) {
      float4* dst = (float4*)(Pg + (size_t)r * SEQ);
      for (int c = kz0 / 4 + tid; c < SEQ / 4; c += 256) dst[c] = make_float4(0.f, 0.f, 0.f, 0.f);
    }
  }
}

extern "C" void kernel_launch(void* const* d_in, const int* in_sizes, int n_in,
                              void* d_out, int out_size, void* d_ws, size_t ws_size,
                              hipStream_t stream) {
  const float* x = (const float*)d_in[0];
  const float* Wq = (const float*)d_in[1];
  const float* Wk = (const float*)d_in[2];
  const float* Wv = (const float*)d_in[3];
  const float* Wo = (const float*)d_in[4];
  const float* bias = (const float*)d_in[5];

  float* out = (float*)d_out;
  float* P = out + (size_t)BATCH * SEQ * HID;  // attn_weights section (written last by k_attn)
  // park projection intermediates inside the not-yet-written P region
  float* Qf = P;
  float* Kf = P + (size_t)BATCH * SEQ * HID;
  bf16_t* Vr = (bf16_t*)(P + 2 * (size_t)BATCH * SEQ * HID);

  char* w = (char*)d_ws;
  bf16_t* xb = (bf16_t*)w;  w += (size_t)BATCH * SEQ * HID * 2;
  bf16_t* Wqb = (bf16_t*)w; w += (size_t)HID * HID * 2;   // Wq/Wk/Wv contiguous ->
  bf16_t* Wkb = (bf16_t*)w; w += (size_t)HID * HID * 2;   // one [6144,2048] matrix
  bf16_t* Wvb = (bf16_t*)w; w += (size_t)HID * HID * 2;
  bf16_t* Wob = (bf16_t*)w; w += (size_t)HID * HID * 2;
  bf16_t* Qb = (bf16_t*)w;  w += (size_t)BATCH * SEQ * HID * 2;
  bf16_t* Kb = (bf16_t*)w;  w += (size_t)BATCH * SEQ * HID * 2;
  bf16_t* Vt = (bf16_t*)w;  w += (size_t)BATCH * SEQ * HID * 2;
  bf16_t* AO = (bf16_t*)w;  w += (size_t)BATCH * SEQ * HID * 2;
  float* bm = (float*)w;    w += (size_t)SEQ * 4;
  // bf16 bias reuses the xb slot (xb dead after the projection GEMM; 8 MB <= 16 MB)
  bf16_t* Bb = xb;

  const int n4x = BATCH * SEQ * HID / 4;
  const int n4w = HID * HID / 4;
  const int n4b = SEQ * SEQ / 4;
  k_cast_bf16<<<(n4x + 255) / 256, 256, 0, stream>>>((const float4*)x, (ushort4*)xb, n4x);
  k_cast_bf16<<<(n4w + 255) / 256, 256, 0, stream>>>((const float4*)Wq, (ushort4*)Wqb, n4w);
  k_cast_bf16<<<(n4w + 255) / 256, 256, 0, stream>>>((const float4*)Wk, (ushort4*)Wkb, n4w);
  k_cast_bf16<<<(n4w + 255) / 256, 256, 0, stream>>>((const float4*)Wv, (ushort4*)Wvb, n4w);
  k_cast_bf16<<<(n4w + 255) / 256, 256, 0, stream>>>((const float4*)Wo, (ushort4*)Wob, n4w);
  k_bmean<<<SEQ, 256, 0, stream>>>(bias, bm);

  // fused QKV projection: N = 6144 (Wqb/Wkb/Wvb contiguous)
  k_gemm_qkv<<<dim3(3 * HID / 128, BATCH * SEQ / 128), 256, 0, stream>>>(xb, Wqb, Qf, Kf, Vr);

  // xb is dead now; cast bias (fp32) -> bf16 into its slot
  k_cast_bf16<<<(n4b + 255) / 256, 256, 0, stream>>>((const float4*)bias, (ushort4*)Bb, n4b);

  k_vtrans<<<dim3(SEQ / 64, HID / 64, BATCH), 256, 0, stream>>>(Vr, Vt);
  k_rope<<<(BATCH * SEQ * HID / 8) / 256, 256, 0, stream>>>(Qf, Kf, bm, Qb, Kb);

  k_attn<<<dim3(16, NH, BATCH), 256, 0, stream>>>(Qb, Kb, Vt, Bb, P, AO);

  k_gemm_bt<0><<<dim3(HID / 128, BATCH * SEQ / 128), 256, 0, stream>>>(AO, Wob, out, BATCH * SEQ, HID, HID);
}